// Round 6
// baseline (429.581 us; speedup 1.0000x reference)
//
#include <hip/hip_runtime.h>
#include <cstdint>

// out = in + 0.1f * N(0,1) where N(0,1) reproduces
// jax.random.normal(jax.random.key(42), (64,3,512,512), f32)
// with jax_threefry_partitionable=True (default since JAX 0.4.36):
//   (x0,x1) = threefry2x32( key=(0,42), ctr=(hi=0, lo=i) )   [i = flat index]
//   bits[i] = x0 ^ x1                         // prng.py: bits1 ^ bits2 for 32-bit
//   f = bitcast((bits>>9)|0x3F800000) - 1.0f  // [0,1)
//   u = max(lo, f*2.0f + lo), lo = nextafter(-1,0) = -0.99999994f
//       ((hi-lo) = 1.99999994 rounds to exactly 2.0f; f*2.0f is exact, so
//        fmaf(f,2.0f,lo) is bit-identical to XLA's separate mul+add)
//   n = sqrt2_f32 * erfinv(u)                 // XLA ErfInv32 (Giles) constants
//   out = in + 0.1f * n

__device__ __forceinline__ uint32_t rotl32(uint32_t x, uint32_t r) {
    return (x << r) | (x >> (32u - r));
}

// Threefry-2x32, 20 rounds, key (0, 42); returns x0 ^ x1 (JAX 32-bit draw).
__device__ __forceinline__ uint32_t threefry_xor(uint32_t ctr_lo) {
    const uint32_t K0 = 0u;
    const uint32_t K1 = 42u;
    const uint32_t K2 = 0x1BD11BDAu ^ K0 ^ K1;   // 0x1BD11BF0
    uint32_t x0 = 0u + K0;        // ctr_hi = 0
    uint32_t x1 = ctr_lo + K1;
#define TF_R(r) { x0 += x1; x1 = rotl32(x1, r); x1 ^= x0; }
    TF_R(13) TF_R(15) TF_R(26) TF_R(6)
    x0 += K1; x1 += K2 + 1u;
    TF_R(17) TF_R(29) TF_R(16) TF_R(24)
    x0 += K2; x1 += K0 + 2u;
    TF_R(13) TF_R(15) TF_R(26) TF_R(6)
    x0 += K0; x1 += K1 + 3u;
    TF_R(17) TF_R(29) TF_R(16) TF_R(24)
    x0 += K1; x1 += K2 + 4u;
    TF_R(13) TF_R(15) TF_R(26) TF_R(6)
    x0 += K2; x1 += K0 + 5u;
#undef TF_R
    return x0 ^ x1;
}

// XLA f32 ErfInv (Giles 2010 polynomial), exact XLA constants.
__device__ __forceinline__ float erfinv32(float x) {
    float w = -log1pf(-x * x);
    float p;
    if (w < 5.0f) {
        w -= 2.5f;
        p = 2.81022636e-08f;
        p = fmaf(p, w, 3.43273939e-07f);
        p = fmaf(p, w, -3.5233877e-06f);
        p = fmaf(p, w, -4.39150654e-06f);
        p = fmaf(p, w, 0.00021858087f);
        p = fmaf(p, w, -0.00125372503f);
        p = fmaf(p, w, -0.00417768164f);
        p = fmaf(p, w, 0.246640727f);
        p = fmaf(p, w, 1.50140941f);
    } else {
        w = sqrtf(w) - 3.0f;
        p = -0.000200214257f;
        p = fmaf(p, w, 0.000100950558f);
        p = fmaf(p, w, 0.00134934322f);
        p = fmaf(p, w, -0.00367342844f);
        p = fmaf(p, w, 0.00573950773f);
        p = fmaf(p, w, -0.0076224613f);
        p = fmaf(p, w, 0.00943887047f);
        p = fmaf(p, w, 1.00167406f);
        p = fmaf(p, w, 2.83297682f);
    }
    return p * x;
}

__global__ __launch_bounds__(256) void noise_add_kernel(
    const float* __restrict__ in, float* __restrict__ out, unsigned n4) {
    unsigned t = blockIdx.x * blockDim.x + threadIdx.x;
    if (t >= n4) return;

    const float4 v = reinterpret_cast<const float4*>(in)[t];
    const uint32_t base = t * 4u;

    const float lo    = -0.99999994f;   // nextafter(-1, 0) in f32
    const float sqrt2 = 1.41421356f;    // np.float32(np.sqrt(2)) = 0x3FB504F3

    float r[4];
    const float vi[4] = {v.x, v.y, v.z, v.w};
#pragma unroll
    for (int k = 0; k < 4; ++k) {
        uint32_t bits = threefry_xor(base + (uint32_t)k);
        uint32_t fb   = (bits >> 9) | 0x3F800000u;
        float f = __uint_as_float(fb) - 1.0f;       // [0, 1)
        float u = fmaf(f, 2.0f, lo);                // exact-mul + single-round add
        u = fmaxf(u, lo);
        float n = sqrt2 * erfinv32(u);
        r[k] = fmaf(0.1f, n, vi[k]);
    }

    float4 o;
    o.x = r[0]; o.y = r[1]; o.z = r[2]; o.w = r[3];
    reinterpret_cast<float4*>(out)[t] = o;
}

extern "C" void kernel_launch(void* const* d_in, const int* in_sizes, int n_in,
                              void* d_out, int out_size, void* d_ws, size_t ws_size,
                              hipStream_t stream) {
    const float* in = (const float*)d_in[0];
    float* out = (float*)d_out;
    const unsigned n  = (unsigned)in_sizes[0];   // 50331648, divisible by 4
    const unsigned n4 = n / 4u;
    const unsigned block = 256;
    const unsigned grid = (n4 + block - 1) / block;
    noise_add_kernel<<<grid, block, 0, stream>>>(in, out, n4);
}